// Round 3
// baseline (455.478 us; speedup 1.0000x reference)
//
#include <hip/hip_runtime.h>
#include <cstdint>
#include <cstddef>

typedef _Float16 v8h __attribute__((ext_vector_type(8)));
typedef _Float16 v4h __attribute__((ext_vector_type(4)));
typedef float v4f __attribute__((ext_vector_type(4)));

#define NH 16
#define HD 128
#define SLEN 2048
#define BATCH 2
#define HID 2048

// async global->LDS, 16B per lane. LDS dest is wave-uniform base + lane*16.
__device__ __forceinline__ void gload16(const void* gptr, void* lptr) {
  __builtin_amdgcn_global_load_lds(
      (const __attribute__((address_space(1))) unsigned int*)gptr,
      (__attribute__((address_space(3))) unsigned int*)lptr, 16, 0, 0);
}

// ---------------------------------------------------------------------------
// small prep kernels
// ---------------------------------------------------------------------------

__global__ __launch_bounds__(256) void cast_x_kernel(const float* __restrict__ in,
                                                     _Float16* __restrict__ out, int n4) {
  int i = blockIdx.x * 256 + threadIdx.x;
  if (i >= n4) return;
  const float4 v = ((const float4*)in)[i];
  v4h o; o[0] = (_Float16)v.x; o[1] = (_Float16)v.y; o[2] = (_Float16)v.z; o[3] = (_Float16)v.w;
  *(v4h*)(out + (size_t)i * 4) = o;
}

// W [R][C] fp32 -> WT [C][R] f16
__global__ __launch_bounds__(256) void transpose_cast_kernel(const float* __restrict__ W,
                                                             _Float16* __restrict__ WT,
                                                             int R, int C) {
  __shared__ float tl[32][33];
  int tx = threadIdx.x, ty = threadIdx.y;
  int c0 = blockIdx.x * 32, r0 = blockIdx.y * 32;
#pragma unroll
  for (int i = 0; i < 4; ++i)
    tl[ty + i * 8][tx] = W[(size_t)(r0 + ty + i * 8) * C + c0 + tx];
  __syncthreads();
#pragma unroll
  for (int i = 0; i < 4; ++i)
    WT[(size_t)(c0 + ty + i * 8) * R + r0 + tx] = (_Float16)tl[tx][ty + i * 8];
}

// V [bh][S][HD] f16 -> VT [bh][HD][S] f16
__global__ __launch_bounds__(256) void transpose_v_kernel(const _Float16* __restrict__ V,
                                                          _Float16* __restrict__ VT) {
  __shared__ _Float16 tl[32][33];
  int tx = threadIdx.x, ty = threadIdx.y;
  int s0 = blockIdx.x * 32, d0 = blockIdx.y * 32;
  int bh = blockIdx.z;
  const _Float16* Vp = V + (size_t)bh * SLEN * HD;
  _Float16* Tp = VT + (size_t)bh * HD * SLEN;
#pragma unroll
  for (int i = 0; i < 4; ++i)
    tl[ty + i * 8][tx] = Vp[(size_t)(s0 + ty + i * 8) * HD + d0 + tx];
  __syncthreads();
#pragma unroll
  for (int i = 0; i < 4; ++i)
    Tp[(size_t)(d0 + ty + i * 8) * SLEN + s0 + tx] = tl[tx][ty + i * 8];
}

__global__ void rope_table_kernel(float* __restrict__ cost, float* __restrict__ sint) {
  int s = blockIdx.x, i = threadIdx.x;  // 2048 blocks x 64 threads
  float inv = powf(10000.0f, -(float)i * (1.0f / 64.0f));
  float ang = (float)s * inv;
  cost[s * 64 + i] = cosf(ang);
  sint[s * 64 + i] = sinf(ang);
}

// in-place GPT-NeoX rope on Q and K, layout [bh][S][HD], vectorized x8
__global__ __launch_bounds__(256) void rope_apply_kernel(_Float16* __restrict__ Q,
                                                         _Float16* __restrict__ K,
                                                         const float* __restrict__ cost,
                                                         const float* __restrict__ sint) {
  int idx = blockIdx.x * 256 + threadIdx.x;  // [0, 32*2048*8)
  int dg = (idx & 7) * 8;
  int s = (idx >> 3) & (SLEN - 1);
  int bh = idx >> 14;
  size_t base = ((size_t)bh * SLEN + s) * HD;
  float4 c0 = *(const float4*)(cost + s * 64 + dg);
  float4 c1 = *(const float4*)(cost + s * 64 + dg + 4);
  float4 s0 = *(const float4*)(sint + s * 64 + dg);
  float4 s1 = *(const float4*)(sint + s * 64 + dg + 4);
  float cc[8] = {c0.x, c0.y, c0.z, c0.w, c1.x, c1.y, c1.z, c1.w};
  float ss[8] = {s0.x, s0.y, s0.z, s0.w, s1.x, s1.y, s1.z, s1.w};
  {
    v8h qa = *(const v8h*)(Q + base + dg);
    v8h qb = *(const v8h*)(Q + base + dg + 64);
#pragma unroll
    for (int j = 0; j < 8; ++j) {
      float a = (float)qa[j], b = (float)qb[j];
      qa[j] = (_Float16)(a * cc[j] - b * ss[j]);
      qb[j] = (_Float16)(b * cc[j] + a * ss[j]);
    }
    *(v8h*)(Q + base + dg) = qa;
    *(v8h*)(Q + base + dg + 64) = qb;
  }
  {
    v8h ka = *(const v8h*)(K + base + dg);
    v8h kb = *(const v8h*)(K + base + dg + 64);
#pragma unroll
    for (int j = 0; j < 8; ++j) {
      float a = (float)ka[j], b = (float)kb[j];
      ka[j] = (_Float16)(a * cc[j] - b * ss[j]);
      kb[j] = (_Float16)(b * cc[j] + a * ss[j]);
    }
    *(v8h*)(K + base + dg) = ka;
    *(v8h*)(K + base + dg + 64) = kb;
  }
}

// ---------------------------------------------------------------------------
// GEMM: C[M,N] = A[M,K] * B[K,N] with BT [N][K] given. f16 in, fp32 accum.
// 128x128 tile, BK=64, 4 waves, double-buffered global_load_lds staging with
// inverse-swizzled per-lane sources (linear LDS dest, XOR-swizzled reads),
// one barrier per K-step. 1D grid with XCD-chunked decode.
// MODE 0: QKV epilogue routing q/k/v per head (f16). MODE 1: fp32 store.
// ---------------------------------------------------------------------------
template <int MODE>
__global__ __launch_bounds__(256) void gemm_kernel(const _Float16* __restrict__ A,
                                                   const _Float16* __restrict__ BT,
                                                   int M, int N, int K, int gy,
                                                   _Float16* __restrict__ q_out,
                                                   _Float16* __restrict__ k_out,
                                                   _Float16* __restrict__ v_out,
                                                   float* __restrict__ f_out) {
  __shared__ alignas(16) char As[2][16384];
  __shared__ alignas(16) char Bs[2][16384];
  const int t = threadIdx.x;
  const int w = t >> 6;
  const int l = t & 63;
  const int wr = w >> 1, wc = w & 1;

  const int total = gridDim.x;
  const int F = blockIdx.x;
  const int gid = (F & 7) * (total >> 3) + (F >> 3);
  const int bx = gid / gy, by = gid % gy;
  const int m0 = by * 128;
  const int n0 = bx * 128;

  // per-lane inverse-swizzled staging sources (tile [128 rows][64 f16])
  const char* aS[4];
  const char* bS[4];
  {
    const int Kb = K * 2;
#pragma unroll
    for (int j = 0; j < 4; ++j) {
      int c = w * 256 + j * 64 + l;
      int row = c >> 3;
      int col = ((c & 7) * 16) ^ ((row & 7) << 4);
      aS[j] = (const char*)A + (size_t)(m0 + row) * Kb + col;
      bS[j] = (const char*)BT + (size_t)(n0 + row) * Kb + col;
    }
  }

  const v4f vzero = {0.f, 0.f, 0.f, 0.f};
  v4f acc[4][4];
#pragma unroll
  for (int mi = 0; mi < 4; ++mi)
#pragma unroll
    for (int ni = 0; ni < 4; ++ni) acc[mi][ni] = vzero;

  auto stage = [&](int ks, int d) {
#pragma unroll
    for (int j = 0; j < 4; ++j) {
      gload16(aS[j] + ks * 128, &As[d][w * 4096 + j * 1024]);
      gload16(bS[j] + ks * 128, &Bs[d][w * 4096 + j * 1024]);
    }
  };

  const int nk = K >> 6;
  stage(0, 0);
  for (int ks = 0; ks < nk; ++ks) {
    asm volatile("s_waitcnt vmcnt(0)" ::: "memory");
    __syncthreads();
    if (ks + 1 < nk) stage(ks + 1, (ks + 1) & 1);
    const char* Ap = As[ks & 1];
    const char* Bp = Bs[ks & 1];
#pragma unroll
    for (int kk = 0; kk < 2; ++kk) {
      v8h a[4], b[4];
#pragma unroll
      for (int mi = 0; mi < 4; ++mi) {
        int row = wr * 64 + mi * 16 + (l & 15);
        a[mi] = *(const v8h*)(Ap + row * 128 + ((kk * 64 + ((l >> 4) * 16)) ^ ((row & 7) << 4)));
      }
#pragma unroll
      for (int ni = 0; ni < 4; ++ni) {
        int row = wc * 64 + ni * 16 + (l & 15);
        b[ni] = *(const v8h*)(Bp + row * 128 + ((kk * 64 + ((l >> 4) * 16)) ^ ((row & 7) << 4)));
      }
      __builtin_amdgcn_s_setprio(1);
#pragma unroll
      for (int mi = 0; mi < 4; ++mi)
#pragma unroll
        for (int ni = 0; ni < 4; ++ni)
          acc[mi][ni] = __builtin_amdgcn_mfma_f32_16x16x32_f16(a[mi], b[ni], acc[mi][ni], 0, 0, 0);
      __builtin_amdgcn_s_setprio(0);
    }
  }

#pragma unroll
  for (int mi = 0; mi < 4; ++mi) {
#pragma unroll
    for (int ni = 0; ni < 4; ++ni) {
      int n = n0 + wc * 64 + ni * 16 + (l & 15);
#pragma unroll
      for (int r = 0; r < 4; ++r) {
        int m = m0 + wr * 64 + mi * 16 + (l >> 4) * 4 + r;
        float v = acc[mi][ni][r];
        if (MODE == 1) {
          f_out[(size_t)m * N + n] = v;
        } else {
          int head = n / 384;
          int rem = n - head * 384;
          int seg = rem >> 7;
          int d = rem & 127;
          int s = m >> 1, bb = m & 1;
          _Float16* dst = (seg == 0) ? q_out : (seg == 1) ? k_out : v_out;
          dst[(((size_t)(bb * NH + head)) * SLEN + s) * HD + d] = (_Float16)v;
        }
      }
    }
  }
}

// ---------------------------------------------------------------------------
// Flash attention (causal), load-balanced pairs (pr, 31-pr) sharing staged K/V.
// This round: A/B tiles processed PHASE-FUSED (QK both -> softmax both ->
// PV both) with separate P buffers; K/V LDS reads shared between tiles.
// ---------------------------------------------------------------------------
__global__ __launch_bounds__(256) void attn_kernel(const _Float16* __restrict__ Qb,
                                                   const _Float16* __restrict__ Kb,
                                                   const _Float16* __restrict__ VTb,
                                                   _Float16* __restrict__ ctx) {
  __shared__ alignas(16) char Ks[2][16384];  // [64 keys][128 d] swizzled rows of 256B
  __shared__ alignas(16) char Vs[2][16384];  // [128 d][64 keys] swizzled rows of 128B
  __shared__ alignas(16) char Ps[2][8192];   // per-wave 16x64 f16 (swizzled), A and B
  const int t = threadIdx.x;
  const int w = t >> 6;
  const int l = t & 63;
  const int F = blockIdx.x;                  // [0,512)
  const int bh = (F & 7) + 8 * ((F >> 3) & 3);
  const int pr = F >> 5;                     // pair index 0..15
  const int ta = pr, tb = 31 - pr;

  const _Float16* Qp = Qb + (size_t)bh * SLEN * HD;
  const _Float16* Kp = Kb + (size_t)bh * SLEN * HD;
  const _Float16* Vp = VTb + (size_t)bh * HD * SLEN;

  // per-lane inverse-swizzled staging sources
  const char* kS[4];
  const char* vS[4];
#pragma unroll
  for (int j = 0; j < 4; ++j) {
    int c = w * 256 + j * 64 + l;
    {
      int row = c >> 4;
      int col = ((c & 15) * 16) ^ ((row & 7) << 4);
      kS[j] = (const char*)Kp + (size_t)row * 256 + col;
    }
    {
      int row = c >> 3;
      int col = ((c & 7) * 16) ^ ((row & 7) << 4);
      vS[j] = (const char*)Vp + (size_t)row * (SLEN * 2) + col;
    }
  }
  auto stage = [&](int kt, int d) {
#pragma unroll
    for (int j = 0; j < 4; ++j) {
      gload16(kS[j] + (size_t)kt * 16384, &Ks[d][w * 4096 + j * 1024]);
      gload16(vS[j] + (size_t)kt * 128, &Vs[d][w * 4096 + j * 1024]);
    }
  };

  // hoist Q fragments for both tiles
  v8h qA[4], qB[4];
  {
    int rA = ta * 64 + w * 16 + (l & 15);
    int rB = tb * 64 + w * 16 + (l & 15);
#pragma unroll
    for (int kk = 0; kk < 4; ++kk) {
      qA[kk] = *(const v8h*)(Qp + (size_t)rA * HD + kk * 32 + (l >> 4) * 8);
      qB[kk] = *(const v8h*)(Qp + (size_t)rB * HD + kk * 32 + (l >> 4) * 8);
    }
  }

  const v4f vzero = {0.f, 0.f, 0.f, 0.f};
  v4f oA[8], oB[8];
#pragma unroll
  for (int df = 0; df < 8; ++df) { oA[df] = vzero; oB[df] = vzero; }
  float mA[4], lA[4], mB[4], lB[4];
#pragma unroll
  for (int r = 0; r < 4; ++r) { mA[r] = -1e30f; lA[r] = 0.f; mB[r] = -1e30f; lB[r] = 0.f; }

  char* PwA = &Ps[0][w * 2048];
  char* PwB = &Ps[1][w * 2048];
  const float scale = 0.08838834764831845f;  // 1/sqrt(128)

  stage(0, 0);
  for (int kt = 0; kt <= tb; ++kt) {
    asm volatile("s_waitcnt vmcnt(0)" ::: "memory");
    __syncthreads();
    if (kt < tb) stage(kt + 1, (kt + 1) & 1);
    const char* Kst = Ks[kt & 1];
    const char* Vst = Vs[kt & 1];
    const bool doA = (kt <= ta);

    // ---- QK^T for both tiles, K-fragment reads shared ----
    v4f sA[4], sB[4];
#pragma unroll
    for (int nf = 0; nf < 4; ++nf) { sA[nf] = vzero; sB[nf] = vzero; }
    __builtin_amdgcn_s_setprio(1);
#pragma unroll
    for (int nf = 0; nf < 4; ++nf) {
      int krow = nf * 16 + (l & 15);
#pragma unroll
      for (int kk = 0; kk < 4; ++kk) {
        v8h kf = *(const v8h*)(Kst + krow * 256 +
                               ((kk * 64 + ((l >> 4) * 16)) ^ ((krow & 7) << 4)));
        if (doA) sA[nf] = __builtin_amdgcn_mfma_f32_16x16x32_f16(qA[kk], kf, sA[nf], 0, 0, 0);
        sB[nf] = __builtin_amdgcn_mfma_f32_16x16x32_f16(qB[kk], kf, sB[nf], 0, 0, 0);
      }
    }
    __builtin_amdgcn_s_setprio(0);

    // ---- scale + causal mask ----
    const bool diagA = (kt == ta), diagB = (kt == tb);
#pragma unroll
    for (int nf = 0; nf < 4; ++nf) {
#pragma unroll
      for (int r = 0; r < 4; ++r) {
        int kg = kt * 64 + nf * 16 + (l & 15);
        if (doA) {
          float s = sA[nf][r] * scale;
          if (diagA && kg > ta * 64 + w * 16 + (l >> 4) * 4 + r) s = -1e4f;
          sA[nf][r] = s;
        }
        {
          float s = sB[nf][r] * scale;
          if (diagB && kg > tb * 64 + w * 16 + (l >> 4) * 4 + r) s = -1e4f;
          sB[nf][r] = s;
        }
      }
    }

    // ---- online softmax, two independent chains interleaved ----
    float alA[4], alB[4];
#pragma unroll
    for (int r = 0; r < 4; ++r) {
      float mvA, mvB;
      if (doA) mvA = fmaxf(fmaxf(sA[0][r], sA[1][r]), fmaxf(sA[2][r], sA[3][r]));
      mvB = fmaxf(fmaxf(sB[0][r], sB[1][r]), fmaxf(sB[2][r], sB[3][r]));
#pragma unroll
      for (int off = 1; off < 16; off <<= 1) {
        if (doA) mvA = fmaxf(mvA, __shfl_xor(mvA, off));
        mvB = fmaxf(mvB, __shfl_xor(mvB, off));
      }
      float mnA, mnB;
      if (doA) { mnA = fmaxf(mA[r], mvA); alA[r] = __expf(mA[r] - mnA); mA[r] = mnA; }
      mnB = fmaxf(mB[r], mvB); alB[r] = __expf(mB[r] - mnB); mB[r] = mnB;
      float rsA = 0.f, rsB = 0.f;
#pragma unroll
      for (int nf = 0; nf < 4; ++nf) {
        if (doA) { float p = __expf(sA[nf][r] - mnA); sA[nf][r] = p; rsA += p; }
        float p = __expf(sB[nf][r] - mnB); sB[nf][r] = p; rsB += p;
      }
#pragma unroll
      for (int off = 1; off < 16; off <<= 1) {
        if (doA) rsA += __shfl_xor(rsA, off);
        rsB += __shfl_xor(rsB, off);
      }
      if (doA) lA[r] = lA[r] * alA[r] + rsA;
      lB[r] = lB[r] * alB[r] + rsB;
    }

    // ---- P (f16) -> per-wave LDS (C-layout -> A-layout transpose) ----
#pragma unroll
    for (int nf = 0; nf < 4; ++nf) {
      int key = nf * 16 + (l & 15);
#pragma unroll
      for (int r = 0; r < 4; ++r) {
        int prow = (l >> 4) * 4 + r;
        int off = prow * 128 + ((key * 2) ^ ((prow & 7) << 4));
        if (doA) *(_Float16*)(PwA + off) = (_Float16)sA[nf][r];
        *(_Float16*)(PwB + off) = (_Float16)sB[nf][r];
      }
    }

    // ---- rescale O (VALU, overlaps ds_write drain) ----
#pragma unroll
    for (int df = 0; df < 8; ++df)
#pragma unroll
      for (int r = 0; r < 4; ++r) {
        if (doA) oA[df][r] *= alA[r];
        oB[df][r] *= alB[r];
      }
    asm volatile("s_waitcnt lgkmcnt(0)" ::: "memory");
    __builtin_amdgcn_sched_barrier(0);

    // ---- O += P * V, V-fragment reads shared ----
    __builtin_amdgcn_s_setprio(1);
#pragma unroll
    for (int kk2 = 0; kk2 < 2; ++kk2) {
      int prow = l & 15;
      int poff = prow * 128 + ((kk2 * 64 + ((l >> 4) * 16)) ^ ((prow & 7) << 4));
      v8h paA, paB;
      if (doA) paA = *(const v8h*)(PwA + poff);
      paB = *(const v8h*)(PwB + poff);
#pragma unroll
      for (int df = 0; df < 8; ++df) {
        int dd = df * 16 + (l & 15);
        v8h vf = *(const v8h*)(Vst + dd * 128 +
                               ((kk2 * 64 + ((l >> 4) * 16)) ^ ((dd & 7) << 4)));
        if (doA) oA[df] = __builtin_amdgcn_mfma_f32_16x16x32_f16(paA, vf, oA[df], 0, 0, 0);
        oB[df] = __builtin_amdgcn_mfma_f32_16x16x32_f16(paB, vf, oB[df], 0, 0, 0);
      }
    }
    __builtin_amdgcn_s_setprio(0);
  }

  // epilogue: normalize and write ctx [(s*B+b)][h*128+d]
  const int b = bh >> 4;
  const int h = bh & 15;
#pragma unroll
  for (int df = 0; df < 8; ++df) {
    int dd = df * 16 + (l & 15);
#pragma unroll
    for (int r = 0; r < 4; ++r) {
      int sA_ = ta * 64 + w * 16 + (l >> 4) * 4 + r;
      ctx[((size_t)(sA_ * BATCH + b)) * HID + h * HD + dd] = (_Float16)(oA[df][r] / lA[r]);
      int sB_ = tb * 64 + w * 16 + (l >> 4) * 4 + r;
      ctx[((size_t)(sB_ * BATCH + b)) * HID + h * HD + dd] = (_Float16)(oB[df][r] / lB[r]);
    }
  }
}

// ---------------------------------------------------------------------------

extern "C" void kernel_launch(void* const* d_in, const int* in_sizes, int n_in,
                              void* d_out, int out_size, void* d_ws, size_t ws_size,
                              hipStream_t stream) {
  const float* x = (const float*)d_in[0];
  const float* w_qkv = (const float*)d_in[1];
  const float* w_dense = (const float*)d_in[2];
  float* out = (float*)d_out;
  char* ws = (char*)d_ws;

  _Float16* xb    = (_Float16*)(ws);               // 4096x2048        16 MB
  _Float16* wqkvT = (_Float16*)(ws + 16777216);    // 6144x2048        24 MB
  _Float16* wdT   = (_Float16*)(ws + 41943040);    // 2048x2048         8 MB
  _Float16* Qb    = (_Float16*)(ws + 50331648);    // [32][2048][128]  16 MB
  _Float16* Kb    = (_Float16*)(ws + 67108864);    // [32][2048][128]  16 MB
  _Float16* Vb    = (_Float16*)(ws + 83886080);    // [32][2048][128]  16 MB
  _Float16* VTb   = (_Float16*)(ws + 100663296);   // [32][128][2048]  16 MB
  _Float16* ctx   = (_Float16*)(ws + 117440512);   // 4096x2048        16 MB
  float* cost     = (float*)(ws + 134217728);      // 2048x64 fp32
  float* sint     = (float*)(ws + 134742016);      // 2048x64 fp32

  cast_x_kernel<<<dim3(8192), dim3(256), 0, stream>>>(x, xb, 2097152);
  transpose_cast_kernel<<<dim3(192, 64), dim3(32, 8), 0, stream>>>(w_qkv, wqkvT, 2048, 6144);
  transpose_cast_kernel<<<dim3(64, 64), dim3(32, 8), 0, stream>>>(w_dense, wdT, 2048, 2048);
  rope_table_kernel<<<dim3(2048), dim3(64), 0, stream>>>(cost, sint);

  gemm_kernel<0><<<dim3(1536), dim3(256), 0, stream>>>(xb, wqkvT, 4096, 6144, 2048, 32,
                                                       Qb, Kb, Vb, (float*)nullptr);
  rope_apply_kernel<<<dim3(2048), dim3(256), 0, stream>>>(Qb, Kb, cost, sint);
  transpose_v_kernel<<<dim3(64, 4, 32), dim3(32, 8), 0, stream>>>(Vb, VTb);
  attn_kernel<<<dim3(512), dim3(256), 0, stream>>>(Qb, Kb, VTb, ctx);
  gemm_kernel<1><<<dim3(512), dim3(256), 0, stream>>>(ctx, wdT, 4096, 2048, 2048, 32,
                                                      (_Float16*)nullptr, (_Float16*)nullptr,
                                                      (_Float16*)nullptr, out);
}

// Round 6
// 284.057 us; speedup vs baseline: 1.6035x; 1.6035x over previous
//
#include <hip/hip_runtime.h>
#include <cstdint>
#include <cstddef>

typedef _Float16 v8h __attribute__((ext_vector_type(8)));
typedef _Float16 v4h __attribute__((ext_vector_type(4)));
typedef _Float16 v2h __attribute__((ext_vector_type(2)));
typedef float v4f __attribute__((ext_vector_type(4)));
typedef float v16f __attribute__((ext_vector_type(16)));

#define NH 16
#define HD 128
#define SLEN 2048
#define BATCH 2
#define HID 2048

// async global->LDS, 16B per lane. LDS dest is wave-uniform base + lane*16.
__device__ __forceinline__ void gload16(const void* gptr, void* lptr) {
  __builtin_amdgcn_global_load_lds(
      (const __attribute__((address_space(1))) unsigned int*)gptr,
      (__attribute__((address_space(3))) unsigned int*)lptr, 16, 0, 0);
}

__device__ __forceinline__ uint32_t pkh(float a, float b) {
  return __builtin_bit_cast(uint32_t, __builtin_amdgcn_cvt_pkrtz(a, b));
}
__device__ __forceinline__ v2h pkh2(float a, float b) {
  return __builtin_bit_cast(v2h, __builtin_amdgcn_cvt_pkrtz(a, b));
}
// unambiguous cross-half (lane ^ 32) exchange via ds_bpermute
__device__ __forceinline__ uint32_t xswap32(uint32_t x) {
  return (uint32_t)__shfl_xor((int)x, 32, 64);
}

// ---------------------------------------------------------------------------
// small prep kernels
// ---------------------------------------------------------------------------

__global__ __launch_bounds__(256) void cast_x_kernel(const float* __restrict__ in,
                                                     _Float16* __restrict__ out, int n4) {
  int i = blockIdx.x * 256 + threadIdx.x;
  if (i >= n4) return;
  const float4 v = ((const float4*)in)[i];
  v4h o; o[0] = (_Float16)v.x; o[1] = (_Float16)v.y; o[2] = (_Float16)v.z; o[3] = (_Float16)v.w;
  *(v4h*)(out + (size_t)i * 4) = o;
}

// W [R][C] fp32 -> WT [C][R] f16
__global__ __launch_bounds__(256) void transpose_cast_kernel(const float* __restrict__ W,
                                                             _Float16* __restrict__ WT,
                                                             int R, int C) {
  __shared__ float tl[32][33];
  int tx = threadIdx.x, ty = threadIdx.y;
  int c0 = blockIdx.x * 32, r0 = blockIdx.y * 32;
#pragma unroll
  for (int i = 0; i < 4; ++i)
    tl[ty + i * 8][tx] = W[(size_t)(r0 + ty + i * 8) * C + c0 + tx];
  __syncthreads();
#pragma unroll
  for (int i = 0; i < 4; ++i)
    WT[(size_t)(c0 + ty + i * 8) * R + r0 + tx] = (_Float16)tl[tx][ty + i * 8];
}

// V [bh][S][HD] f16 -> VT [bh][HD][S] f16
__global__ __launch_bounds__(256) void transpose_v_kernel(const _Float16* __restrict__ V,
                                                          _Float16* __restrict__ VT) {
  __shared__ _Float16 tl[32][33];
  int tx = threadIdx.x, ty = threadIdx.y;
  int s0 = blockIdx.x * 32, d0 = blockIdx.y * 32;
  int bh = blockIdx.z;
  const _Float16* Vp = V + (size_t)bh * SLEN * HD;
  _Float16* Tp = VT + (size_t)bh * HD * SLEN;
#pragma unroll
  for (int i = 0; i < 4; ++i)
    tl[ty + i * 8][tx] = Vp[(size_t)(s0 + ty + i * 8) * HD + d0 + tx];
  __syncthreads();
#pragma unroll
  for (int i = 0; i < 4; ++i)
    Tp[(size_t)(d0 + ty + i * 8) * SLEN + s0 + tx] = tl[tx][ty + i * 8];
}

__global__ void rope_table_kernel(float* __restrict__ cost, float* __restrict__ sint) {
  int s = blockIdx.x, i = threadIdx.x;  // 2048 blocks x 64 threads
  float inv = powf(10000.0f, -(float)i * (1.0f / 64.0f));
  float ang = (float)s * inv;
  cost[s * 64 + i] = cosf(ang);
  sint[s * 64 + i] = sinf(ang);
}

// in-place GPT-NeoX rope on Q and K, layout [bh][S][HD], vectorized x8
__global__ __launch_bounds__(256) void rope_apply_kernel(_Float16* __restrict__ Q,
                                                         _Float16* __restrict__ K,
                                                         const float* __restrict__ cost,
                                                         const float* __restrict__ sint) {
  int idx = blockIdx.x * 256 + threadIdx.x;  // [0, 32*2048*8)
  int dg = (idx & 7) * 8;
  int s = (idx >> 3) & (SLEN - 1);
  int bh = idx >> 14;
  size_t base = ((size_t)bh * SLEN + s) * HD;
  float4 c0 = *(const float4*)(cost + s * 64 + dg);
  float4 c1 = *(const float4*)(cost + s * 64 + dg + 4);
  float4 s0 = *(const float4*)(sint + s * 64 + dg);
  float4 s1 = *(const float4*)(sint + s * 64 + dg + 4);
  float cc[8] = {c0.x, c0.y, c0.z, c0.w, c1.x, c1.y, c1.z, c1.w};
  float ss[8] = {s0.x, s0.y, s0.z, s0.w, s1.x, s1.y, s1.z, s1.w};
  {
    v8h qa = *(const v8h*)(Q + base + dg);
    v8h qb = *(const v8h*)(Q + base + dg + 64);
#pragma unroll
    for (int j = 0; j < 8; ++j) {
      float a = (float)qa[j], b = (float)qb[j];
      qa[j] = (_Float16)(a * cc[j] - b * ss[j]);
      qb[j] = (_Float16)(b * cc[j] + a * ss[j]);
    }
    *(v8h*)(Q + base + dg) = qa;
    *(v8h*)(Q + base + dg + 64) = qb;
  }
  {
    v8h ka = *(const v8h*)(K + base + dg);
    v8h kb = *(const v8h*)(K + base + dg + 64);
#pragma unroll
    for (int j = 0; j < 8; ++j) {
      float a = (float)ka[j], b = (float)kb[j];
      ka[j] = (_Float16)(a * cc[j] - b * ss[j]);
      kb[j] = (_Float16)(b * cc[j] + a * ss[j]);
    }
    *(v8h*)(K + base + dg) = ka;
    *(v8h*)(K + base + dg + 64) = kb;
  }
}

// ---------------------------------------------------------------------------
// GEMM (unchanged from round 2): 128x128 tile, BK=64, 4 waves, dbuf
// global_load_lds staging, swizzled LDS, XCD-chunked 1D grid.
// ---------------------------------------------------------------------------
template <int MODE>
__global__ __launch_bounds__(256) void gemm_kernel(const _Float16* __restrict__ A,
                                                   const _Float16* __restrict__ BT,
                                                   int M, int N, int K, int gy,
                                                   _Float16* __restrict__ q_out,
                                                   _Float16* __restrict__ k_out,
                                                   _Float16* __restrict__ v_out,
                                                   float* __restrict__ f_out) {
  __shared__ alignas(16) char As[2][16384];
  __shared__ alignas(16) char Bs[2][16384];
  const int t = threadIdx.x;
  const int w = t >> 6;
  const int l = t & 63;
  const int wr = w >> 1, wc = w & 1;

  const int total = gridDim.x;
  const int F = blockIdx.x;
  const int gid = (F & 7) * (total >> 3) + (F >> 3);
  const int bx = gid / gy, by = gid % gy;
  const int m0 = by * 128;
  const int n0 = bx * 128;

  const char* aS[4];
  const char* bS[4];
  {
    const int Kb = K * 2;
#pragma unroll
    for (int j = 0; j < 4; ++j) {
      int c = w * 256 + j * 64 + l;
      int row = c >> 3;
      int col = ((c & 7) * 16) ^ ((row & 7) << 4);
      aS[j] = (const char*)A + (size_t)(m0 + row) * Kb + col;
      bS[j] = (const char*)BT + (size_t)(n0 + row) * Kb + col;
    }
  }

  const v4f vzero = {0.f, 0.f, 0.f, 0.f};
  v4f acc[4][4];
#pragma unroll
  for (int mi = 0; mi < 4; ++mi)
#pragma unroll
    for (int ni = 0; ni < 4; ++ni) acc[mi][ni] = vzero;

  auto stage = [&](int ks, int d) {
#pragma unroll
    for (int j = 0; j < 4; ++j) {
      gload16(aS[j] + ks * 128, &As[d][w * 4096 + j * 1024]);
      gload16(bS[j] + ks * 128, &Bs[d][w * 4096 + j * 1024]);
    }
  };

  const int nk = K >> 6;
  stage(0, 0);
  for (int ks = 0; ks < nk; ++ks) {
    asm volatile("s_waitcnt vmcnt(0)" ::: "memory");
    __syncthreads();
    if (ks + 1 < nk) stage(ks + 1, (ks + 1) & 1);
    const char* Ap = As[ks & 1];
    const char* Bp = Bs[ks & 1];
#pragma unroll
    for (int kk = 0; kk < 2; ++kk) {
      v8h a[4], b[4];
#pragma unroll
      for (int mi = 0; mi < 4; ++mi) {
        int row = wr * 64 + mi * 16 + (l & 15);
        a[mi] = *(const v8h*)(Ap + row * 128 + ((kk * 64 + ((l >> 4) * 16)) ^ ((row & 7) << 4)));
      }
#pragma unroll
      for (int ni = 0; ni < 4; ++ni) {
        int row = wc * 64 + ni * 16 + (l & 15);
        b[ni] = *(const v8h*)(Bp + row * 128 + ((kk * 64 + ((l >> 4) * 16)) ^ ((row & 7) << 4)));
      }
      __builtin_amdgcn_s_setprio(1);
#pragma unroll
      for (int mi = 0; mi < 4; ++mi)
#pragma unroll
        for (int ni = 0; ni < 4; ++ni)
          acc[mi][ni] = __builtin_amdgcn_mfma_f32_16x16x32_f16(a[mi], b[ni], acc[mi][ni], 0, 0, 0);
      __builtin_amdgcn_s_setprio(0);
    }
  }

#pragma unroll
  for (int mi = 0; mi < 4; ++mi) {
#pragma unroll
    for (int ni = 0; ni < 4; ++ni) {
      int n = n0 + wc * 64 + ni * 16 + (l & 15);
#pragma unroll
      for (int r = 0; r < 4; ++r) {
        int m = m0 + wr * 64 + mi * 16 + (l >> 4) * 4 + r;
        float v = acc[mi][ni][r];
        if (MODE == 1) {
          f_out[(size_t)m * N + n] = v;
        } else {
          int head = n / 384;
          int rem = n - head * 384;
          int seg = rem >> 7;
          int d = rem & 127;
          int s = m >> 1, bb = m & 1;
          _Float16* dst = (seg == 0) ? q_out : (seg == 1) ? k_out : v_out;
          dst[(((size_t)(bb * NH + head)) * SLEN + s) * HD + d] = (_Float16)v;
        }
      }
    }
  }
}

// ---------------------------------------------------------------------------
// Flash attention, 32x32-mfma swapped-QK^T structure.
// Block = 4 waves; waves 0-1 own q-tile ta (2x32 rows), waves 2-3 own tb.
// Per lane: one q-row (col = lane&31), 64 key-scores in 32 regs ->
// softmax fully in-register. Cross-half exchanges via __shfl_xor(.,32)
// (ds_bpermute; unambiguous semantics). PV computes O^T via
// mfma(VT_frag, P_frag); P built in-register with cvt_pkrtz + xswap.
// K/V double-buffered global_load_lds staging; XCD-pinned bh.
// ---------------------------------------------------------------------------
__global__ __launch_bounds__(256, 2) void attn_kernel(const _Float16* __restrict__ Qb,
                                                      const _Float16* __restrict__ Kb,
                                                      const _Float16* __restrict__ VTb,
                                                      _Float16* __restrict__ ctx) {
  __shared__ alignas(16) char Ks[2][16384];  // [64 keys][128 d] swizzled rows of 256B
  __shared__ alignas(16) char Vs[2][16384];  // [128 d][64 keys] swizzled rows of 128B
  const int t = threadIdx.x;
  const int w = t >> 6;
  const int l = t & 63;
  const int F = blockIdx.x;                  // [0,512)
  const int bh = (F & 7) + 8 * ((F >> 3) & 3);
  const int pr = F >> 5;                     // pair index 0..15
  const int ta = pr, tb = 31 - pr;
  const int grp = w >> 1;                    // 0 -> tile ta, 1 -> tile tb
  const int tile = grp ? tb : ta;
  const int q0 = tile * 64 + (w & 1) * 32;
  const int l31 = l & 31, g = l >> 5;
  const int q = q0 + l31;                    // this lane's q row

  const _Float16* Qp = Qb + (size_t)bh * SLEN * HD;
  const _Float16* Kp = Kb + (size_t)bh * SLEN * HD;
  const _Float16* Vp = VTb + (size_t)bh * HD * SLEN;

  // per-lane inverse-swizzled staging sources (verbatim round-2 pattern)
  const char* kS[4];
  const char* vS[4];
#pragma unroll
  for (int j = 0; j < 4; ++j) {
    int c = w * 256 + j * 64 + l;
    {
      int row = c >> 4;
      int col = ((c & 15) * 16) ^ ((row & 7) << 4);
      kS[j] = (const char*)Kp + (size_t)row * 256 + col;
    }
    {
      int row = c >> 3;
      int col = ((c & 7) * 16) ^ ((row & 7) << 4);
      vS[j] = (const char*)Vp + (size_t)row * (SLEN * 2) + col;
    }
  }
  auto stage = [&](int kt, int d) {
#pragma unroll
    for (int j = 0; j < 4; ++j) {
      gload16(kS[j] + (size_t)kt * 16384, &Ks[d][w * 4096 + j * 1024]);
      gload16(vS[j] + (size_t)kt * 128, &Vs[d][w * 4096 + j * 1024]);
    }
  };

  // hoist Q: B-frag chunks, chunk c covers d = 16c + 8g + j
  v8h qf[8];
#pragma unroll
  for (int c = 0; c < 8; ++c)
    qf[c] = *(const v8h*)(Qp + (size_t)q * HD + c * 16 + g * 8);

  v16f oT[4];
#pragma unroll
  for (int dc = 0; dc < 4; ++dc)
#pragma unroll
    for (int r = 0; r < 16; ++r) oT[dc][r] = 0.f;
  float m_run = -1e30f, l_run = 0.f;
  const float scale = 0.08838834764831845f;  // 1/sqrt(128)

  stage(0, 0);
  for (int kt = 0; kt <= tb; ++kt) {
    asm volatile("s_waitcnt vmcnt(0)" ::: "memory");
    __syncthreads();
    if (kt < tb) stage(kt + 1, (kt + 1) & 1);
    if (grp == 0 && kt > ta) continue;       // wave-uniform skip
    const char* Kst = Ks[kt & 1];
    const char* Vst = Vs[kt & 1];

    // ---- S^T = K * Q^T : two 32-key halves, 8 d-chunks each ----
    v16f s0, s1;
#pragma unroll
    for (int r = 0; r < 16; ++r) { s0[r] = 0.f; s1[r] = 0.f; }
    __builtin_amdgcn_s_setprio(1);
#pragma unroll
    for (int c = 0; c < 8; ++c) {
      int cofs = (c * 32 + g * 16);
      v8h kf0 = *(const v8h*)(Kst + l31 * 256 + (cofs ^ ((l31 & 7) << 4)));
      v8h kf1 = *(const v8h*)(Kst + (32 + l31) * 256 + (cofs ^ ((l31 & 7) << 4)));
      s0 = __builtin_amdgcn_mfma_f32_32x32x16_f16(kf0, qf[c], s0, 0, 0, 0);
      s1 = __builtin_amdgcn_mfma_f32_32x32x16_f16(kf1, qf[c], s1, 0, 0, 0);
    }
    __builtin_amdgcn_s_setprio(0);

    // ---- scale + causal mask; pv[i] holds key kv0 + 32*(i>>4) + kofs ----
    const bool diag = (kt == tile);
    const int kv0 = kt * 64;
    float pv[32];
#pragma unroll
    for (int r = 0; r < 16; ++r) {
      int kofs = (r & 3) + 8 * (r >> 2) + 4 * g;
      float a = s0[r] * scale;
      float b = s1[r] * scale;
      if (diag) {
        if (kv0 + kofs > q) a = -1e4f;
        if (kv0 + 32 + kofs > q) b = -1e4f;
      }
      pv[r] = a;
      pv[16 + r] = b;
    }

    // ---- row max: in-lane tree + cross-half merge ----
    float mx[8];
#pragma unroll
    for (int i = 0; i < 8; ++i)
      mx[i] = fmaxf(fmaxf(pv[i], pv[i + 8]), fmaxf(pv[i + 16], pv[i + 24]));
    float pm = fmaxf(fmaxf(fmaxf(mx[0], mx[1]), fmaxf(mx[2], mx[3])),
                     fmaxf(fmaxf(mx[4], mx[5]), fmaxf(mx[6], mx[7])));
    float pmall = fmaxf(pm, __shfl_xor(pm, 32, 64));

    // ---- defer-max (T13, THR=8) ----
    float mnew;
    if (__all(pmall - m_run <= 8.f)) {
      mnew = m_run;
    } else {
      mnew = fmaxf(m_run, pmall);
      float alpha = __expf(m_run - mnew);
      m_run = mnew;
      l_run *= alpha;
#pragma unroll
      for (int dc = 0; dc < 4; ++dc)
#pragma unroll
        for (int r = 0; r < 16; ++r) oT[dc][r] *= alpha;
    }

    // ---- exp + row sum ----
    float sacc0 = 0.f, sacc1 = 0.f, sacc2 = 0.f, sacc3 = 0.f;
#pragma unroll
    for (int i = 0; i < 8; ++i) { pv[i] = __expf(pv[i] - mnew); sacc0 += pv[i]; }
#pragma unroll
    for (int i = 8; i < 16; ++i) { pv[i] = __expf(pv[i] - mnew); sacc1 += pv[i]; }
#pragma unroll
    for (int i = 16; i < 24; ++i) { pv[i] = __expf(pv[i] - mnew); sacc2 += pv[i]; }
#pragma unroll
    for (int i = 24; i < 32; ++i) { pv[i] = __expf(pv[i] - mnew); sacc3 += pv[i]; }
    float ssum = (sacc0 + sacc1) + (sacc2 + sacc3);
    l_run += ssum + __shfl_xor(ssum, 32, 64);

    // ---- O^T += VT * P^T : P-frags via cvt_pk + cross-half exchange ----
    // pf slot (g,j) must hold key c*16 + g*8 + j. Own regs cover:
    //   g=0: keys base..base+3 (P0,P1), base+4g-range held by partner.
    // send: g=0 sends P2,P3 (partner needs them in lo); g=1 sends P0,P1.
    __builtin_amdgcn_s_setprio(1);
#pragma unroll
    for (int c = 0; c < 4; ++c) {          // key chunk of 16
      int base = (c >> 1) * 16 + (c & 1) * 8;
      uint32_t P0 = pkh(pv[base + 0], pv[base + 1]);
      uint32_t P1 = pkh(pv[base + 2], pv[base + 3]);
      uint32_t P2 = pkh(pv[base + 4], pv[base + 5]);
      uint32_t P3 = pkh(pv[base + 6], pv[base + 7]);
      uint32_t T0 = g ? P0 : P2;
      uint32_t T1 = g ? P1 : P3;
      uint32_t U0 = xswap32(T0);
      uint32_t U1 = xswap32(T1);
      union { uint32_t u[4]; v8h h; } pu;
      pu.u[0] = g ? U0 : P0;
      pu.u[1] = g ? U1 : P1;
      pu.u[2] = g ? P2 : U0;
      pu.u[3] = g ? P3 : U1;
      v8h pf = pu.h;
      int cofs = c * 32 + g * 16;
#pragma unroll
      for (int dc = 0; dc < 4; ++dc) {
        int vrow = dc * 32 + l31;
        v8h vf = *(const v8h*)(Vst + vrow * 128 + (cofs ^ ((vrow & 7) << 4)));
        oT[dc] = __builtin_amdgcn_mfma_f32_32x32x16_f16(vf, pf, oT[dc], 0, 0, 0);
      }
    }
    __builtin_amdgcn_s_setprio(0);
  }

  // ---- epilogue: O^T col q per lane; divide by l and store ----
  const float inv = 1.0f / l_run;
  const int b = bh >> 4;
  const int hh = bh & 15;
  _Float16* orow = ctx + ((size_t)q * BATCH + b) * HID + hh * HD;
#pragma unroll
  for (int dc = 0; dc < 4; ++dc) {
#pragma unroll
    for (int rr = 0; rr < 4; ++rr) {
      v2h w0 = pkh2(oT[dc][4 * rr + 0] * inv, oT[dc][4 * rr + 1] * inv);
      v2h w1 = pkh2(oT[dc][4 * rr + 2] * inv, oT[dc][4 * rr + 3] * inv);
      v4h o4; o4[0] = w0[0]; o4[1] = w0[1]; o4[2] = w1[0]; o4[3] = w1[1];
      *(v4h*)(orow + dc * 32 + rr * 8 + g * 4) = o4;
    }
  }
}

// ---------------------------------------------------------------------------

extern "C" void kernel_launch(void* const* d_in, const int* in_sizes, int n_in,
                              void* d_out, int out_size, void* d_ws, size_t ws_size,
                              hipStream_t stream) {
  const float* x = (const float*)d_in[0];
  const float* w_qkv = (const float*)d_in[1];
  const float* w_dense = (const float*)d_in[2];
  float* out = (float*)d_out;
  char* ws = (char*)d_ws;

  _Float16* xb    = (_Float16*)(ws);               // 4096x2048        16 MB
  _Float16* wqkvT = (_Float16*)(ws + 16777216);    // 6144x2048        24 MB
  _Float16* wdT   = (_Float16*)(ws + 41943040);    // 2048x2048         8 MB
  _Float16* Qb    = (_Float16*)(ws + 50331648);    // [32][2048][128]  16 MB
  _Float16* Kb    = (_Float16*)(ws + 67108864);    // [32][2048][128]  16 MB
  _Float16* Vb    = (_Float16*)(ws + 83886080);    // [32][2048][128]  16 MB
  _Float16* VTb   = (_Float16*)(ws + 100663296);   // [32][128][2048]  16 MB
  _Float16* ctx   = (_Float16*)(ws + 117440512);   // 4096x2048        16 MB
  float* cost     = (float*)(ws + 134217728);      // 2048x64 fp32
  float* sint     = (float*)(ws + 134742016);      // 2048x64 fp32

  cast_x_kernel<<<dim3(8192), dim3(256), 0, stream>>>(x, xb, 2097152);
  transpose_cast_kernel<<<dim3(192, 64), dim3(32, 8), 0, stream>>>(w_qkv, wqkvT, 2048, 6144);
  transpose_cast_kernel<<<dim3(64, 64), dim3(32, 8), 0, stream>>>(w_dense, wdT, 2048, 2048);
  rope_table_kernel<<<dim3(2048), dim3(64), 0, stream>>>(cost, sint);

  gemm_kernel<0><<<dim3(1536), dim3(256), 0, stream>>>(xb, wqkvT, 4096, 6144, 2048, 32,
                                                       Qb, Kb, Vb, (float*)nullptr);
  rope_apply_kernel<<<dim3(2048), dim3(256), 0, stream>>>(Qb, Kb, cost, sint);
  transpose_v_kernel<<<dim3(64, 4, 32), dim3(32, 8), 0, stream>>>(Vb, VTb);
  attn_kernel<<<dim3(512), dim3(256), 0, stream>>>(Qb, Kb, VTb, ctx);
  gemm_kernel<1><<<dim3(512), dim3(256), 0, stream>>>(ctx, wdT, 4096, 2048, 2048, 32,
                                                      (_Float16*)nullptr, (_Float16*)nullptr,
                                                      (_Float16*)nullptr, out);
}